// Round 10
// baseline (86.774 us; speedup 1.0000x reference)
//
#include <hip/hip_runtime.h>
#include <hip/hip_bf16.h>

#define NN 16384
#define DD 128
#define TS 64                  // strip height == tile size (64x64 tiles)
#define NS 256                 // number of strips
#define NTILES 32896           // NS*(NS+1)/2 triangular tiles
#define NB 1024                // blocks (contiguous rank ranges of ~32)
#define SQRT_SCALE 4.5398159622f   // sqrt(log2(e)/0.07); dot of scaled vecs == exp2 arg

// Schraudolph exp2: exp2(y) ~= bitcast<f32>((int)(y*2^23 + (127*2^23 - C)))
#define EXP_A 8388608.0f       // 2^23
#define EXP_K 1064986316.0f    // 127*2^23 - C, C=366585 (min max-rel-err +-3%)

typedef __attribute__((ext_vector_type(8))) short bf16x8;
typedef __attribute__((ext_vector_type(4))) float f32x4;

// T(s) = number of triangular tiles before strip s
#define TRI(s) (256 * (s) - ((s) * ((s)-1)) / 2)

// ---------------- Kernel 1: fp32 -> scaled bf16, swizzled layout ---------------
// 16B chunk c of row r stored at chunk position (c ^ (r&15)); linear global->LDS
// staging then yields bank-conflict-free ds_read_b128 fragment reads.
__global__ void convert_swz(const float* __restrict__ x, ushort* __restrict__ xb) {
    int t = blockIdx.x * blockDim.x + threadIdx.x;   // one thread per 8-elem chunk
    int r = t >> 4;
    int c = t & 15;
    const float4* src = (const float4*)(x + (size_t)r * DD + c * 8);
    float4 f0 = src[0];
    float4 f1 = src[1];
    float vals[8] = {f0.x, f0.y, f0.z, f0.w, f1.x, f1.y, f1.z, f1.w};
    bf16x8 v;
#pragma unroll
    for (int i = 0; i < 8; ++i) {
        __hip_bfloat16 h = __float2bfloat16(vals[i] * SQRT_SCALE);
        v[i] = (short)__builtin_bit_cast(unsigned short, h);
    }
    int cs = c ^ (r & 15);
    *(bf16x8*)(xb + (size_t)r * DD + cs * 8) = v;
}

// ---------------- Kernel 2: triangular streaming X·X^T -> exp2 -> sums ---------
// 1024 blocks x 256 threads (4 waves = 4 colwaves of one 64-row strip).
// Block b owns triangular tile ranks [b*NTILES/NB, (b+1)*NTILES/NB): ~32 tiles,
// perfectly balanced. Per tile (s,ct): 16 MFMA vs in-register af (strip s rows),
// B slice wave-private double-buffered in LDS (R8 structure, barrier-free,
// counted vmcnt). Row sums in registers, lane-reduced + atomicAdd at strip
// change; col sums (symmetry) by atomicAdd per tile (skipped on diagonal).
__global__ __launch_bounds__(256, 4) void gemm_exp_tri(const ushort* __restrict__ xb,
                                                       float* __restrict__ rowsum) {
    __shared__ __align__(16) char lds[4][2][4096];   // [wave][buf][4KB slice]

    const int tid  = threadIdx.x;
    const int lane = tid & 63;
    const int cw   = tid >> 6;       // 0..3 colwave
    const int frow = lane & 15;
    const int kq   = lane >> 4;

    char* myL = &lds[cw][0][0];

    const int bid = blockIdx.x;
    const int R0 = (int)(((long long)bid * NTILES) >> 10);
    const int R1 = (int)(((long long)(bid + 1) * NTILES) >> 10);
    const int n  = R1 - R0;          // 32 or 33

    // ---- unrank R0 -> (s, ct) ----
    int s = (int)(256.5f - sqrtf(256.5f * 256.5f - 2.0f * (float)R0));
    if (s < 0) s = 0;
    if (s > 255) s = 255;
    while (s < 255 && TRI(s + 1) <= R0) ++s;
    while (s > 0 && TRI(s) > R0) --s;
    int ct = s + (R0 - TRI(s));

    // Stage the wave's 16-col slice of tile ct into private buf (4x 1KB gll).
    auto stage = [&](int buf, int c) {
        const char* g = (const char*)(xb + (size_t)(c * TS + cw * 16) * DD);
#pragma unroll
        for (int j = 0; j < 4; ++j) {
            __builtin_amdgcn_global_load_lds(
                (const __attribute__((address_space(1))) unsigned int*)(g + j * 1024 + lane * 16),
                (__attribute__((address_space(3))) unsigned int*)(myL + buf * 4096 + j * 1024),
                16, 0, 0);
        }
    };

    // ---- prefetch cursor, 2 tiles ahead ----
    int ps = s, pc = ct;
    stage(0, pc);
    if (pc == 255) { ++ps; pc = ps; } else ++pc;
    stage(1, pc);
    if (pc == 255) { ++ps; pc = ps; } else ++pc;

    // ---- A fragments for strip s: 64 rows, K=128, in registers ----
    bf16x8 af[4][4];
    auto load_af = [&](int ss) {
#pragma unroll
        for (int m = 0; m < 4; ++m)
#pragma unroll
            for (int kk = 0; kk < 4; ++kk) {
                int ra = ss * TS + m * 16 + frow;       // ra & 15 == frow
                int slot = (kk * 4 + kq) ^ frow;
                af[m][kk] = *(const bf16x8*)(xb + (size_t)ra * DD + slot * 8);
            }
    };
    load_af(s);

    // ---- per-kk LDS byte offsets within the private 4KB slice ----
    int roff[4];
#pragma unroll
    for (int kk = 0; kk < 4; ++kk)
        roff[kk] = frow * 256 + ((((kk << 2) + kq) ^ frow) << 4);

    asm volatile("s_waitcnt vmcnt(0)" ::: "memory");   // af + 2 staged tiles

    const f32x4 zacc = {0.f, 0.f, 0.f, 0.f};
    float rs[4][4] = {};

    // Reduce rs over the wave's 16 col-lanes, then atomicAdd rows of strip ss.
    auto flush_rows = [&](int ss) {
#pragma unroll
        for (int m = 0; m < 4; ++m)
#pragma unroll
            for (int j = 0; j < 4; ++j) {
                float v = rs[m][j];
                v += __shfl_xor(v, 1);
                v += __shfl_xor(v, 2);
                v += __shfl_xor(v, 4);
                v += __shfl_xor(v, 8);
                rs[m][j] = v;
            }
        if (frow == 0) {
#pragma unroll
            for (int m = 0; m < 4; ++m)
#pragma unroll
                for (int j = 0; j < 4; ++j)
                    atomicAdd(&rowsum[ss * TS + m * 16 + kq * 4 + j], rs[m][j]);
        }
    };

    for (int q = 0; q < n; ++q) {
        const int cur = q & 1;
        const char* Bb = myL + cur * 4096;

        f32x4 acc[4];
        __builtin_amdgcn_s_setprio(1);
#pragma unroll
        for (int kk = 0; kk < 4; ++kk) {
            bf16x8 bfr = *(const bf16x8*)(Bb + roff[kk]);
            if (kk == 0) {
#pragma unroll
                for (int m = 0; m < 4; ++m)
                    acc[m] = __builtin_amdgcn_mfma_f32_16x16x32_bf16(
                        af[m][0], bfr, zacc, 0, 0, 0);
            } else {
#pragma unroll
                for (int m = 0; m < 4; ++m)
                    acc[m] = __builtin_amdgcn_mfma_f32_16x16x32_bf16(
                        af[m][kk], bfr, acc[m], 0, 0, 0);
            }
        }
        __builtin_amdgcn_s_setprio(0);

        // MFMA deps retired all ds_reads of buf cur: safe to restage it (t+2).
        __builtin_amdgcn_sched_barrier(0);
        if (q + 2 < n) {
            stage(cur, pc);
            if (pc == 255) { ++ps; pc = ps; } else ++pc;
        }

        // ---- epilogue: Schraudolph exp2 (pure VALU) + row & col partial sums --
        float cs = 0.f;
#pragma unroll
        for (int m = 0; m < 4; ++m)
#pragma unroll
            for (int j = 0; j < 4; ++j) {
                float b = __builtin_fmaf(acc[m][j], EXP_A, EXP_K);
                float e = __builtin_bit_cast(float, (int)b);
                rs[m][j] += e;
                cs += e;
            }
        // col-sum over the 64 rows (combine the 4 kq groups), skip on diagonal
        cs += __shfl_xor(cs, 16);
        cs += __shfl_xor(cs, 32);
        if (ct != s && kq == 0)
            atomicAdd(&rowsum[ct * TS + cw * 16 + frow], cs);

        // ---- advance compute cursor; handle strip boundary ----
        if (q + 1 < n) {
            int olds = s;
            if (ct == 255) { ++s; ct = s; } else ++ct;
            if (s != olds) {
                // flush row sums of finished strip, reload af, drain loads
                flush_rows(olds);
#pragma unroll
                for (int m = 0; m < 4; ++m)
#pragma unroll
                    for (int j = 0; j < 4; ++j)
                        rs[m][j] = 0.f;
                load_af(s);
                asm volatile("s_waitcnt vmcnt(0)" ::: "memory");
            } else if (q < n - 2) {
                asm volatile("s_waitcnt vmcnt(4)" ::: "memory");
            } else {
                asm volatile("s_waitcnt vmcnt(0)" ::: "memory");
            }
        }
    }

    // ---- final row-sum flush ----
    flush_rows(s);
}

// ---------------- Kernel 3a: per-row log, 64-block partial sums ----------------
__global__ void finalize_part(const float* __restrict__ rowsum,
                              float* __restrict__ partial) {
    const int tid = threadIdx.x;
    const int r = blockIdx.x * 256 + tid;
    float s = __builtin_amdgcn_logf(rowsum[r]) * 0.69314718056f;
#pragma unroll
    for (int o = 1; o < 64; o <<= 1)
        s += __shfl_xor(s, o);
    __shared__ float wsum[4];
    if ((tid & 63) == 0) wsum[tid >> 6] = s;
    __syncthreads();
    if (tid == 0)
        partial[blockIdx.x] = wsum[0] + wsum[1] + wsum[2] + wsum[3];
}

// ---------------- Kernel 3b: final sum -----------------------------------------
__global__ void finalize_sum(const float* __restrict__ partial, float* __restrict__ out) {
    float s = partial[threadIdx.x];   // 64 threads
#pragma unroll
    for (int o = 1; o < 64; o <<= 1)
        s += __shfl_xor(s, o);
    if (threadIdx.x == 0)
        out[0] = s * (1.0f / NN);
}

extern "C" void kernel_launch(void* const* d_in, const int* in_sizes, int n_in,
                              void* d_out, int out_size, void* d_ws, size_t ws_size,
                              hipStream_t stream) {
    const float* x = (const float*)d_in[0];
    float* out = (float*)d_out;

    ushort* xb     = (ushort*)d_ws;                                // 4 MB scaled bf16
    float* rowsum  = (float*)((char*)d_ws + (size_t)NN * DD * 2);  // 64 KB
    float* partial = rowsum + NN;                                  // 64 floats

    hipMemsetAsync(rowsum, 0, NN * sizeof(float), stream);
    convert_swz<<<(NN * 16) / 256, 256, 0, stream>>>(x, xb);
    gemm_exp_tri<<<NB, 256, 0, stream>>>(xb, rowsum);
    finalize_part<<<64, 256, 0, stream>>>(rowsum, partial);
    finalize_sum<<<1, 64, 0, stream>>>(partial, out);
}